// Round 4
// baseline (16.708 us; speedup 1.0000x reference)
//
#include <hip/hip_runtime.h>

// Grid geometry (compile-time constants from the reference)
#define NXC   2048
#define PMLC  40
#define W     2128                    // NXC + 2*PMLC
#define WV    532                     // float4's per row
#define NWORK (W * WV)                // 1,132,096 vec4-threads
#define NBLK  ((NWORK + 255) / 256)   // 4423 blocks

typedef float f32x4 __attribute__((ext_vector_type(4)));

__global__ __launch_bounds__(256) void wave_step(
    const float* __restrict__ p1,
    const float* __restrict__ p2,
    const float* __restrict__ varray,
    const float* __restrict__ sf,
    const int* __restrict__ xs_p,
    const int* __restrict__ ys_p,
    const int* __restrict__ t_p,
    float* __restrict__ pout,
    float* __restrict__ col)
{
    // Bijective XCD-chunk swizzle (T1, m204): each XCD gets a contiguous
    // band of rows so the up/dn stencil rows hit that XCD's private L2.
    constexpr int q = NBLK / 8, r = NBLK % 8;
    const int xcd = blockIdx.x & 7, pos = blockIdx.x >> 3;
    const int swz = (xcd < r ? xcd * (q + 1) : r * (q + 1) + (xcd - r) * q) + pos;
    const int v = (swz << 8) + (int)threadIdx.x;
    if (v >= NWORK) return;

    const int i  = v / WV;                 // row
    const int j0 = (v - i * WV) << 2;      // first column of this float4
    const size_t base = (size_t)i * W + j0;

    if (i < 8 || i >= W - 8 || j0 < 8 || j0 >= W - 8) {
        // reference zeros everything outside [8, W-8)
        f32x4 z = {0.f, 0.f, 0.f, 0.f};
        __builtin_nontemporal_store(z, reinterpret_cast<f32x4*>(&pout[base]));
        return;
    }

    constexpr float inv_dx2 = 1.0f / (10.0f * 10.0f);
    constexpr float dt2     = 0.0005f * 0.0005f;

    // p2 stays cached (center/up/dn row reuse through L2)
    const f32x4 c  = *reinterpret_cast<const f32x4*>(&p2[base]);
    const f32x4 up = *reinterpret_cast<const f32x4*>(&p2[base - W]);
    const f32x4 dn = *reinterpret_cast<const f32x4*>(&p2[base + W]);
    // p1 is read exactly once -> nontemporal, don't evict p2 rows from L2
    const f32x4 a1 = __builtin_nontemporal_load(
        reinterpret_cast<const f32x4*>(&p1[base]));
    const float lft = p2[base - 1];
    const float rgt = p2[base + 4];

    const int vi = min(max(i - PMLC, 0), NXC - 1);
    const float* __restrict__ vr = &varray[(size_t)vi * NXC];

    // velocity row, edge-padded; vectorized in the common fully-interior case
    float vav[4];
    const int vj0 = j0 - PMLC;
    if (vj0 >= 0 && vj0 <= NXC - 4) {
        const f32x4 vv = __builtin_nontemporal_load(
            reinterpret_cast<const f32x4*>(&vr[vj0]));
        vav[0] = vv.x; vav[1] = vv.y; vav[2] = vv.z; vav[3] = vv.w;
    } else {
        #pragma unroll
        for (int k = 0; k < 4; ++k)
            vav[k] = vr[min(max(vj0 + k, 0), NXC - 1)];
    }

    const float cc[6]  = {lft, c.x, c.y, c.z, c.w, rgt};
    const float upk[4] = {up.x, up.y, up.z, up.w};
    const float dnk[4] = {dn.x, dn.y, dn.z, dn.w};
    const float a1k[4] = {a1.x, a1.y, a1.z, a1.w};
    float outk[4];

    #pragma unroll
    for (int k = 0; k < 4; ++k) {
        const float alpha = vav[k] * vav[k] * dt2;
        const float ctr   = cc[k + 1];
        const float lap   = (cc[k] + cc[k + 2] + upk[k] + dnk[k] - 4.0f * ctr) * inv_dx2;
        outk[k] = 2.0f * ctr - a1k[k] + alpha * lap;
    }

    // Fused source injection. For valid x_s,y_s in [0,2048) the source cell
    // (x_s+40, y_s+40) is always interior, so the owning thread handles it.
    const int xs = xs_p[0] + PMLC;
    const int ys = ys_p[0] + PMLC;
    if (i == xs) {
        const int d = ys - j0;
        if ((unsigned)d < 4u) {
            outk[d] += sf[t_p[0]] * dt2;
        }
    }

    // res[:, 50] = p[PML + r, PML + 50] = p[40 + r, 90]; 90 = j0 88, lane 2
    if (j0 == 88 && (unsigned)(i - PMLC) < (unsigned)NXC) {
        col[i - PMLC] = outk[2];
    }

    f32x4 outv = {outk[0], outk[1], outk[2], outk[3]};
    __builtin_nontemporal_store(outv, reinterpret_cast<f32x4*>(&pout[base]));
}

extern "C" void kernel_launch(void* const* d_in, const int* in_sizes, int n_in,
                              void* d_out, int out_size, void* d_ws, size_t ws_size,
                              hipStream_t stream) {
    const float* p1 = (const float*)d_in[0];
    const float* p2 = (const float*)d_in[1];
    const float* va = (const float*)d_in[2];
    const float* sf = (const float*)d_in[3];
    const int* xs   = (const int*)d_in[4];
    const int* ys   = (const int*)d_in[5];
    const int* t    = (const int*)d_in[6];

    float* pout = (float*)d_out;                   // W*W elements
    float* col  = (float*)d_out + (size_t)W * W;   // 2048 elements

    wave_step<<<NBLK, 256, 0, stream>>>(p1, p2, va, sf, xs, ys, t, pout, col);
}

// Round 5
// 16.287 us; speedup vs baseline: 1.0258x; 1.0258x over previous
//
#include <hip/hip_runtime.h>

// Grid geometry (compile-time constants from the reference)
#define NXC   2048
#define PMLC  40
#define W     2128                     // NXC + 2*PMLC
#define WV    532                      // float4's per row
#define NPAIR (W / 2)                  // 1064 row-pairs
#define NWORK (NPAIR * WV)             // 566,048 vec4-pair threads
#define NBLK  ((NWORK + 255) / 256)    // 2212 blocks

typedef float f32x4 __attribute__((ext_vector_type(4)));

__global__ __launch_bounds__(256) void wave_step(
    const float* __restrict__ p1,
    const float* __restrict__ p2,
    const float* __restrict__ varray,
    const float* __restrict__ sf,
    const int* __restrict__ xs_p,
    const int* __restrict__ ys_p,
    const int* __restrict__ t_p,
    float* __restrict__ pout,
    float* __restrict__ col)
{
    // Bijective XCD-chunk swizzle (T1, m204): each XCD owns a contiguous
    // band of row-pairs so halo rows hit that XCD's private L2.
    constexpr int q = NBLK / 8, r = NBLK % 8;
    const int xcd = blockIdx.x & 7, pos = blockIdx.x >> 3;
    const int swz = (xcd < r ? xcd * (q + 1) : r * (q + 1) + (xcd - r) * q) + pos;
    const int v = (swz << 8) + (int)threadIdx.x;
    if (v >= NWORK) return;

    const int pr = v / WV;                 // row-pair index
    const int i  = pr << 1;                // first row of the pair
    const int j0 = (v - pr * WV) << 2;     // first column of this float4
    const size_t base0 = (size_t)i * W + j0;
    const size_t base1 = base0 + W;

    // Border cuts (8 and 2120) are even -> a pair is uniformly border/interior.
    if (i < 8 || i >= W - 8 || j0 < 8 || j0 >= W - 8) {
        f32x4 z = {0.f, 0.f, 0.f, 0.f};
        *reinterpret_cast<f32x4*>(&pout[base0]) = z;
        *reinterpret_cast<f32x4*>(&pout[base1]) = z;
        return;
    }

    constexpr float inv_dx2 = 1.0f / (10.0f * 10.0f);
    constexpr float dt2     = 0.0005f * 0.0005f;

    // p2 rows i-1 .. i+2 (4 loads serve both output rows)
    const f32x4 rm1 = *reinterpret_cast<const f32x4*>(&p2[base0 - W]);
    const f32x4 r0  = *reinterpret_cast<const f32x4*>(&p2[base0]);
    const f32x4 rp1 = *reinterpret_cast<const f32x4*>(&p2[base1]);
    const f32x4 rp2 = *reinterpret_cast<const f32x4*>(&p2[base1 + W]);
    const f32x4 a10 = *reinterpret_cast<const f32x4*>(&p1[base0]);
    const f32x4 a11 = *reinterpret_cast<const f32x4*>(&p1[base1]);
    const float lft0 = p2[base0 - 1], rgt0 = p2[base0 + 4];
    const float lft1 = p2[base1 - 1], rgt1 = p2[base1 + 4];

    // velocity rows, edge-padded
    const int vi0 = min(max(i - PMLC, 0), NXC - 1);
    const int vi1 = min(max(i + 1 - PMLC, 0), NXC - 1);
    const float* __restrict__ vr0 = &varray[(size_t)vi0 * NXC];
    const float* __restrict__ vr1 = &varray[(size_t)vi1 * NXC];
    float va0[4], va1[4];
    const int vj0 = j0 - PMLC;
    if (vj0 >= 0 && vj0 <= NXC - 4) {
        const f32x4 w0 = *reinterpret_cast<const f32x4*>(&vr0[vj0]);
        const f32x4 w1 = *reinterpret_cast<const f32x4*>(&vr1[vj0]);
        va0[0]=w0.x; va0[1]=w0.y; va0[2]=w0.z; va0[3]=w0.w;
        va1[0]=w1.x; va1[1]=w1.y; va1[2]=w1.z; va1[3]=w1.w;
    } else {
        #pragma unroll
        for (int k = 0; k < 4; ++k) {
            const int vj = min(max(vj0 + k, 0), NXC - 1);
            va0[k] = vr0[vj];
            va1[k] = vr1[vj];
        }
    }

    const float c0[6] = {lft0, r0.x, r0.y, r0.z, r0.w, rgt0};
    const float c1[6] = {lft1, rp1.x, rp1.y, rp1.z, rp1.w, rgt1};
    const float um[4] = {rm1.x, rm1.y, rm1.z, rm1.w};
    const float dp[4] = {rp2.x, rp2.y, rp2.z, rp2.w};
    const float a0k[4] = {a10.x, a10.y, a10.z, a10.w};
    const float a1k[4] = {a11.x, a11.y, a11.z, a11.w};
    float out0[4], out1[4];

    #pragma unroll
    for (int k = 0; k < 4; ++k) {
        // row i: up = rm1, dn = rp1 (== c1 center)
        const float ctr0 = c0[k + 1];
        const float lap0 = (c0[k] + c0[k + 2] + um[k] + c1[k + 1] - 4.0f * ctr0) * inv_dx2;
        out0[k] = 2.0f * ctr0 - a0k[k] + va0[k] * va0[k] * dt2 * lap0;
        // row i+1: up = r0 (== c0 center), dn = rp2
        const float ctr1 = c1[k + 1];
        const float lap1 = (c1[k] + c1[k + 2] + c0[k + 1] + dp[k] - 4.0f * ctr1) * inv_dx2;
        out1[k] = 2.0f * ctr1 - a1k[k] + va1[k] * va1[k] * dt2 * lap1;
    }

    // Fused source injection (source cell is always interior).
    const int xs = xs_p[0] + PMLC;
    const int ys = ys_p[0] + PMLC;
    if (xs - i <= 1 && xs >= i) {
        const int d = ys - j0;
        if ((unsigned)d < 4u) {
            const float add = sf[t_p[0]] * dt2;
            if (xs == i) out0[d] += add; else out1[d] += add;
        }
    }

    // res[:, 50] = p[40 + r, 90]; 90 = j0 88, lane 2
    if (j0 == 88) {
        if ((unsigned)(i - PMLC) < (unsigned)NXC)     col[i - PMLC]     = out0[2];
        if ((unsigned)(i + 1 - PMLC) < (unsigned)NXC) col[i + 1 - PMLC] = out1[2];
    }

    f32x4 o0 = {out0[0], out0[1], out0[2], out0[3]};
    f32x4 o1 = {out1[0], out1[1], out1[2], out1[3]};
    *reinterpret_cast<f32x4*>(&pout[base0]) = o0;
    *reinterpret_cast<f32x4*>(&pout[base1]) = o1;
}

extern "C" void kernel_launch(void* const* d_in, const int* in_sizes, int n_in,
                              void* d_out, int out_size, void* d_ws, size_t ws_size,
                              hipStream_t stream) {
    const float* p1 = (const float*)d_in[0];
    const float* p2 = (const float*)d_in[1];
    const float* va = (const float*)d_in[2];
    const float* sf = (const float*)d_in[3];
    const int* xs   = (const int*)d_in[4];
    const int* ys   = (const int*)d_in[5];
    const int* t    = (const int*)d_in[6];

    float* pout = (float*)d_out;                   // W*W elements
    float* col  = (float*)d_out + (size_t)W * W;   // 2048 elements

    wave_step<<<NBLK, 256, 0, stream>>>(p1, p2, va, sf, xs, ys, t, pout, col);
}

// Round 6
// 16.104 us; speedup vs baseline: 1.0375x; 1.0114x over previous
//
#include <hip/hip_runtime.h>

// Grid geometry (compile-time constants from the reference)
#define NXC   2048
#define PMLC  40
#define W     2128                    // NXC + 2*PMLC
#define WV    532                     // float4's per row
#define NWORK (W * WV)                // 1,132,096 vec4-threads
#define NBLK  ((NWORK + 255) / 256)   // 4423 blocks

typedef float f32x4 __attribute__((ext_vector_type(4)));

__global__ __launch_bounds__(256) void wave_step(
    const float* __restrict__ p1,
    const float* __restrict__ p2,
    const float* __restrict__ varray,
    const float* __restrict__ sf,
    const int* __restrict__ xs_p,
    const int* __restrict__ ys_p,
    const int* __restrict__ t_p,
    float* __restrict__ pout,
    float* __restrict__ col)
{
    // Bijective XCD-chunk swizzle (T1, m204): each XCD owns a contiguous
    // band of rows so halo rows hit that XCD's private L2.
    constexpr int q = NBLK / 8, r = NBLK % 8;
    const int xcd = blockIdx.x & 7, pos = blockIdx.x >> 3;
    const int swz = (xcd < r ? xcd * (q + 1) : r * (q + 1) + (xcd - r) * q) + pos;
    const int v = (swz << 8) + (int)threadIdx.x;
    if (v >= NWORK) return;

    const int i  = v / WV;                 // row
    const int j0 = (v - i * WV) << 2;      // first column of this float4
    const size_t base = (size_t)i * W + j0;

    // Center vector is valid for ALL threads (p2 is the full padded grid).
    // Load it before the border branch so interior lanes can pull lft/rgt
    // from neighbor lanes via shuffle (rows are NOT wave-aligned: border
    // threads at j0<8 / j0>=2120 must still supply their c values).
    const f32x4 c = *reinterpret_cast<const f32x4*>(&p2[base]);
    const int lane = (int)(threadIdx.x & 63);
    float lft = __shfl_up(c.w, 1);     // lane l-1 holds p2[j0-1]
    float rgt = __shfl_down(c.x, 1);   // lane l+1 holds p2[j0+4]

    if (i < 8 || i >= W - 8 || j0 < 8 || j0 >= W - 8) {
        // reference zeros everything outside [8, W-8)
        f32x4 z = {0.f, 0.f, 0.f, 0.f};
        *reinterpret_cast<f32x4*>(&pout[base]) = z;
        return;
    }

    // wave-edge lanes: neighbor vec4 lives in another wave -> real load
    if (lane == 0)  lft = p2[base - 1];
    if (lane == 63) rgt = p2[base + 4];

    constexpr float inv_dx2 = 1.0f / (10.0f * 10.0f);
    constexpr float dt2     = 0.0005f * 0.0005f;

    const f32x4 up = *reinterpret_cast<const f32x4*>(&p2[base - W]);
    const f32x4 dn = *reinterpret_cast<const f32x4*>(&p2[base + W]);
    const f32x4 a1 = *reinterpret_cast<const f32x4*>(&p1[base]);

    const int vi = min(max(i - PMLC, 0), NXC - 1);
    const float* __restrict__ vr = &varray[(size_t)vi * NXC];

    // velocity row, edge-padded; vectorized in the common fully-interior case
    float vav[4];
    const int vj0 = j0 - PMLC;
    if (vj0 >= 0 && vj0 <= NXC - 4) {
        const f32x4 vv = *reinterpret_cast<const f32x4*>(&vr[vj0]);
        vav[0] = vv.x; vav[1] = vv.y; vav[2] = vv.z; vav[3] = vv.w;
    } else {
        #pragma unroll
        for (int k = 0; k < 4; ++k)
            vav[k] = vr[min(max(vj0 + k, 0), NXC - 1)];
    }

    const float cc[6]  = {lft, c.x, c.y, c.z, c.w, rgt};
    const float upk[4] = {up.x, up.y, up.z, up.w};
    const float dnk[4] = {dn.x, dn.y, dn.z, dn.w};
    const float a1k[4] = {a1.x, a1.y, a1.z, a1.w};
    float outk[4];

    #pragma unroll
    for (int k = 0; k < 4; ++k) {
        const float alpha = vav[k] * vav[k] * dt2;
        const float ctr   = cc[k + 1];
        const float lap   = (cc[k] + cc[k + 2] + upk[k] + dnk[k] - 4.0f * ctr) * inv_dx2;
        outk[k] = 2.0f * ctr - a1k[k] + alpha * lap;
    }

    // Fused source injection (source cell (x_s+40, y_s+40) is always interior).
    const int xs = xs_p[0] + PMLC;
    const int ys = ys_p[0] + PMLC;
    if (i == xs) {
        const int d = ys - j0;
        if ((unsigned)d < 4u) {
            outk[d] += sf[t_p[0]] * dt2;
        }
    }

    // res[:, 50] = p[PML + r, PML + 50] = p[40 + r, 90]; 90 = j0 88, lane 2
    if (j0 == 88 && (unsigned)(i - PMLC) < (unsigned)NXC) {
        col[i - PMLC] = outk[2];
    }

    f32x4 outv = {outk[0], outk[1], outk[2], outk[3]};
    *reinterpret_cast<f32x4*>(&pout[base]) = outv;
}

extern "C" void kernel_launch(void* const* d_in, const int* in_sizes, int n_in,
                              void* d_out, int out_size, void* d_ws, size_t ws_size,
                              hipStream_t stream) {
    const float* p1 = (const float*)d_in[0];
    const float* p2 = (const float*)d_in[1];
    const float* va = (const float*)d_in[2];
    const float* sf = (const float*)d_in[3];
    const int* xs   = (const int*)d_in[4];
    const int* ys   = (const int*)d_in[5];
    const int* t    = (const int*)d_in[6];

    float* pout = (float*)d_out;                   // W*W elements
    float* col  = (float*)d_out + (size_t)W * W;   // 2048 elements

    wave_step<<<NBLK, 256, 0, stream>>>(p1, p2, va, sf, xs, ys, t, pout, col);
}